// Round 8
// baseline (66.247 us; speedup 1.0000x reference)
//
#include <hip/hip_runtime.h>
#include <hip/hip_bf16.h>

// Problem constants
#define NB 32      // batch
#define NC 8       // channels
#define NL 512     // length
#define NS 63      // scales
#define NK 1009    // max wavelet kernel length (odd)
#define NPAD 504   // (NK-1)/2
#define ND 512     // d_model
#define NCT 512    // total channels after concat = C*(1+S)
#define NROWS 514  // Apad rows per batch (circular-padded)

typedef __attribute__((ext_vector_type(4))) float f32x4;
typedef __attribute__((ext_vector_type(8))) short short8;
typedef __attribute__((ext_vector_type(4))) short short4v;

// Workspace layout (bytes)
#define APAD_BYTES (NB * NROWS * NL * 2)   // 16,842,752  bf16 [B][514][512]
#define WB_BYTES   (3 * ND * NL * 2)       //  1,572,864  bf16 [3][512][512]
#define BANKB_BYTES (64 * 1024 * 2)        //    131,072  bf16 [64][1024]

typedef const __attribute__((address_space(1))) unsigned int* gp1_t;
typedef __attribute__((address_space(3))) unsigned int* lp3_t;
__device__ __forceinline__ void gload_lds16(const void* g, void* l) {
  __builtin_amdgcn_global_load_lds((gp1_t)g, (lp3_t)l, 16, 0, 0);
}

__device__ __forceinline__ unsigned short bf16_bits(float v) {
  return __builtin_bit_cast(unsigned short, __float2bfloat16(v));
}

#define WAITVM(N) asm volatile("s_waitcnt vmcnt(" #N ")" ::: "memory")
#define FENCE() asm volatile("" ::: "memory")
#define BAR() __builtin_amdgcn_s_barrier()
#define PRIO1() __builtin_amdgcn_s_setprio(1)
#define PRIO0() __builtin_amdgcn_s_setprio(0)

// ---------------------------------------------------------------------------
// Kernel 1: prep — Wb[k][o][l] = bf16(tw[o][l][k]); bankB[s][k] zero-padded.
// ---------------------------------------------------------------------------
__global__ __launch_bounds__(256) void prep_kernel(
    const float* __restrict__ bank, const float* __restrict__ tw,
    __hip_bfloat16* __restrict__ Wb, __hip_bfloat16* __restrict__ bankB) {
  const int idx = blockIdx.x * 256 + threadIdx.x;   // 65536 threads

  {
    int i0 = idx * 4;
    const float4* t4 = (const float4*)(tw + (size_t)i0 * 3);
    float4 a = t4[0], bq = t4[1], c4 = t4[2];
    ushort4 w0 = make_ushort4(bf16_bits(a.x), bf16_bits(a.w), bf16_bits(bq.z), bf16_bits(c4.y));
    ushort4 w1 = make_ushort4(bf16_bits(a.y), bf16_bits(bq.x), bf16_bits(bq.w), bf16_bits(c4.z));
    ushort4 w2 = make_ushort4(bf16_bits(a.z), bf16_bits(bq.y), bf16_bits(c4.x), bf16_bits(c4.w));
    *(ushort4*)(Wb + 0 * ND * NL + i0) = w0;
    *(ushort4*)(Wb + 1 * ND * NL + i0) = w1;
    *(ushort4*)(Wb + 2 * ND * NL + i0) = w2;
  }
  {
    int s = idx >> 10, k = idx & 1023;
    float v = (s < NS && k < NK) ? bank[s * NK + k] : 0.f;
    bankB[idx] = __float2bfloat16(v);
  }
}

// ---------------------------------------------------------------------------
// Kernel 2: cwt via MFMA.  d[t][s] = | sum_k bank[s][k] * dx[t+k] |.
// One block per (b,c): all 64 scales (4 m-frags), 8 waves over t.
// ALL 8 bank K-tiles staged upfront (131 KB); counted-vmcnt ladder.
// Zero-tile skip via compile-time (kt,m) masks — m0:kt2-4, m1:kt1-5,
// m2:kt0-6, m3:all (exact: bank row s zero outside [504-8(s+1), 504+8(s+1)]).
// ---------------------------------------------------------------------------
#define CPY_STRIDE 3088   // 1536*2 + 16 pad

__global__ __launch_bounds__(512) void cwt_kernel(
    const float* __restrict__ x, const __hip_bfloat16* __restrict__ bankB,
    __hip_bfloat16* __restrict__ Apad) {
  __shared__ char smem[8 * 16384 + 4 * CPY_STRIDE];  // 143,424 B
  char* bankS = smem;
  char* cpy = smem + 8 * 16384;

  const int tid = threadIdx.x;
  const int bc = blockIdx.x;
  const int b = bc >> 3, c = bc & 7;
  const int w = tid >> 6, l = tid & 63;
  const int hi = l >> 4, li = l & 15;

  const float* xrow = x + bc * NL;

  // x -> Apad row 1+c (and wrap row 513 from c==0)
  if (tid < 512) {
    __hip_bfloat16 v = __float2bfloat16(xrow[tid]);
    Apad[((size_t)(b * NROWS) + 1 + c) * NL + tid] = v;
    if (c == 0) Apad[((size_t)(b * NROWS) + 513) * NL + tid] = v;
  }

  // stage dx copies: cpy[r][e] = bf16(dx[e+r]), e<1536 (older than bank loads)
  for (int i = 0; i < 6; ++i) {
    int p = tid + i * 512;
    int r_ = p / 768, pe = p - r_ * 768;
    int e0 = 2 * pe;
    int i0 = e0 + r_;
    float xa = (i0 >= NPAD && i0 < NPAD + NL) ? xrow[i0 - NPAD] : 0.f;
    float xb = (i0 + 1 >= NPAD && i0 + 1 < NPAD + NL) ? xrow[i0 + 1 - NPAD] : 0.f;
    float xc = (i0 + 2 >= NPAD && i0 + 2 < NPAD + NL) ? xrow[i0 + 2 - NPAD] : 0.f;
    unsigned short u0 = bf16_bits(xb - xa);
    unsigned short u1 = bf16_bits(xc - xb);
    *(unsigned int*)(cpy + r_ * CPY_STRIDE + e0 * 2) = (unsigned)u0 | ((unsigned)u1 << 16);
  }

#define STAGE(kt)                                                             \
  {                                                                           \
    for (int i = 0; i < 2; ++i) {                                             \
      int ck = tid + i * 512;                                                 \
      int s_ = ck >> 4, rb = ck & 15;                                         \
      int srcc = rb ^ (s_ & 7);                                               \
      gload_lds16(bankB + s_ * 1024 + (kt) * 128 + srcc * 8,                  \
                  bankS + (kt) * 16384 + ck * 16);                            \
    }                                                                         \
  }

#define AVMM(kt, ksl, m)                                                       \
  {                                                                            \
    int srow = (m) * 16 + li;                                                  \
    int chunk = ((ksl) * 4 + hi) ^ (srow & 7);                                 \
    short8 av = *(const short8*)(bankS + (kt) * 16384 + srow * 256 + chunk * 16); \
    _Pragma("unroll") for (int n = 0; n < 4; ++n)                              \
      acc[m][n] = __builtin_amdgcn_mfma_f32_16x16x32_bf16(av, bv[n],           \
                                                          acc[m][n], 0, 0, 0); \
  }

#define CCOMP(kt, M0, M1, M2, M3)                                              \
  {                                                                            \
    _Pragma("unroll") for (int ksl = 0; ksl < 4; ++ksl) {                      \
      short8 bv[4];                                                            \
      _Pragma("unroll") for (int n = 0; n < 4; ++n) {                          \
        int t = tbase + n * 16 + li;                                           \
        int e = t - r + (kt) * 128 + ksl * 32 + hi * 8;                        \
        const char* pc = cpy + r * CPY_STRIDE + e * 2;                         \
        short4v lo = *(const short4v*)pc;                                      \
        short4v hh = *(const short4v*)(pc + 8);                                \
        short8 f;                                                              \
        f[0] = lo[0]; f[1] = lo[1]; f[2] = lo[2]; f[3] = lo[3];                \
        f[4] = hh[0]; f[5] = hh[1]; f[6] = hh[2]; f[7] = hh[3];                \
        bv[n] = f;                                                             \
      }                                                                        \
      PRIO1();                                                                 \
      if (M0) AVMM(kt, ksl, 0);                                                \
      if (M1) AVMM(kt, ksl, 1);                                                \
      if (M2) AVMM(kt, ksl, 2);                                                \
      if (M3) AVMM(kt, ksl, 3);                                                \
      PRIO0();                                                                 \
    }                                                                          \
  }

  // issue ALL 8 tile stages (16 gload_lds in flight)
  STAGE(0); STAGE(1); STAGE(2); STAGE(3);
  STAGE(4); STAGE(5); STAGE(6); STAGE(7);

  f32x4 acc[4][4] = {};
  const int r = l & 3;
  const int tbase = w * 64;

  asm volatile("s_waitcnt vmcnt(14) lgkmcnt(0)" ::: "memory");
  BAR(); FENCE(); CCOMP(0, 0, 0, 1, 1);
  WAITVM(12); BAR(); FENCE(); CCOMP(1, 0, 1, 1, 1);
  WAITVM(10); BAR(); FENCE(); CCOMP(2, 1, 1, 1, 1);
  WAITVM(8);  BAR(); FENCE(); CCOMP(3, 1, 1, 1, 1);
  WAITVM(6);  BAR(); FENCE(); CCOMP(4, 1, 1, 1, 1);
  WAITVM(4);  BAR(); FENCE(); CCOMP(5, 0, 1, 1, 1);
  WAITVM(2);  BAR(); FENCE(); CCOMP(6, 0, 0, 1, 1);
  WAITVM(0);  BAR(); FENCE(); CCOMP(7, 0, 0, 0, 1);

  // epilogue: d = |acc|; lane holds D[s=m*16+hi*4+rg][t=w*64+n*16+li]
#pragma unroll
  for (int m = 0; m < 4; ++m) {
#pragma unroll
    for (int rg = 0; rg < 4; ++rg) {
      int s = m * 16 + hi * 4 + rg;
      if (s >= NS) continue;
      int ch = 8 + c * NS + s;
      size_t rowbase = ((size_t)(b * NROWS) + 1 + ch) * NL;
#pragma unroll
      for (int n = 0; n < 4; ++n) {
        int t = tbase + n * 16 + li;
        float d = fabsf(acc[m][n][rg]);
        __hip_bfloat16 hv = __float2bfloat16(d);
        bool lastgrp = (w == 7 && n == 3);
        bool skip = lastgrp && (li == 15);
        bool dup = lastgrp && (li == 14);
        if (!skip) Apad[rowbase + t] = hv;
        if (dup) Apad[rowbase + 511] = hv;
        if (ch == NCT - 1) {
          size_t wrapbase = (size_t)(b * NROWS) * NL;
          if (!skip) Apad[wrapbase + t] = hv;
          if (dup) Apad[wrapbase + 511] = hv;
        }
      }
    }
  }
#undef STAGE
#undef AVMM
#undef CCOMP
}

// ---------------------------------------------------------------------------
// Kernel 3: gemm — out[b][p][o] = sum_{kap} sum_l Apad[b][p+kap][l]*Wb[kap][o][l]
// 128x128 tile, BK=32 (48 K-steps incl. kap), mfma 16x16x32.
// T4 deep: 5 LDS buffers, stage-3-ahead, vmcnt(12), ONE barrier per step
//          (writer-buf vs laggard-reader-buf differ by 4 mod 5 — safe).
// T2: source-swizzled chunks cg = c ^ ((row>>1)&3), reader same XOR
//     (conflict-free: even/odd rows split bank halves, 8 groups x 8 lanes).
// T5: setprio(1) around the 16-MFMA cluster.
// T1: XCD decode — 4 o-variants of (b,p) share gid%8 -> same XCD L2.
// ---------------------------------------------------------------------------
__global__ __launch_bounds__(256) void gemm_kernel(
    const __hip_bfloat16* __restrict__ Ap, const __hip_bfloat16* __restrict__ Wb,
    float* __restrict__ out) {
  __shared__ __hip_bfloat16 sA[5][128 * 32];   // 40 KB
  __shared__ __hip_bfloat16 sB[5][128 * 32];   // 40 KB  -> 80 KB total, 2 blk/CU

  const int tid = threadIdx.x;
  const int gid = blockIdx.x;          // 0..511
  const int q = gid >> 3;              // 0..63
  const int pid = (gid & 7) * 16 + (q >> 2);  // 0..127
  const int b = pid >> 2;
  const int p0 = (pid & 3) * 128;
  const int o0 = (q & 3) * 128;

  const int w = tid >> 6, lane = tid & 63;
  const int wm = w >> 1, wn = w & 1;
  const int row_in = lane & 15, hi = lane >> 4;

  const int r0 = tid >> 2, cg0 = (tid & 3) ^ ((r0 >> 1) & 3);
  const int ck1 = tid + 256;
  const int r1 = ck1 >> 2, cg1 = (ck1 & 3) ^ ((r1 >> 1) & 3);

#define GSTAGE(kk, bu)                                                         \
  {                                                                            \
    const int kap_ = (kk) >> 4;                                                \
    const int l0_ = ((kk) & 15) << 5;                                          \
    gload_lds16(Ap + ((b * NROWS + p0 + kap_ + r0) * NL + l0_ + cg0 * 8),      \
                &sA[bu][tid * 8]);                                             \
    gload_lds16(Ap + ((b * NROWS + p0 + kap_ + r1) * NL + l0_ + cg1 * 8),      \
                &sA[bu][ck1 * 8]);                                             \
    gload_lds16(Wb + ((kap_ * ND + o0 + r0) * NL + l0_ + cg0 * 8),             \
                &sB[bu][tid * 8]);                                             \
    gload_lds16(Wb + ((kap_ * ND + o0 + r1) * NL + l0_ + cg1 * 8),             \
                &sB[bu][ck1 * 8]);                                             \
  }

#define COMPUTE(bu)                                                            \
  {                                                                            \
    short8 av[4], bv[4];                                                       \
    _Pragma("unroll") for (int m = 0; m < 4; ++m) {                            \
      int row = wm * 64 + m * 16 + row_in;                                     \
      int slot = row * 4 + (hi ^ ((row >> 1) & 3));                            \
      av[m] = *(const short8*)(&sA[bu][slot * 8]);                             \
    }                                                                          \
    _Pragma("unroll") for (int n = 0; n < 4; ++n) {                            \
      int row = wn * 64 + n * 16 + row_in;                                     \
      int slot = row * 4 + (hi ^ ((row >> 1) & 3));                            \
      bv[n] = *(const short8*)(&sB[bu][slot * 8]);                             \
    }                                                                          \
    PRIO1();                                                                   \
    _Pragma("unroll") for (int m = 0; m < 4; ++m)                              \
      _Pragma("unroll") for (int n = 0; n < 4; ++n)                            \
        acc[m][n] = __builtin_amdgcn_mfma_f32_16x16x32_bf16(av[m], bv[n],      \
                                                            acc[m][n], 0, 0, 0); \
    PRIO0();                                                                   \
  }

#define STEP(kk, bu, bs)                                                       \
  GSTAGE((kk) + 3, bs); WAITVM(12); BAR(); FENCE(); COMPUTE(bu); FENCE();

  f32x4 acc[4][4] = {};

  GSTAGE(0, 0); GSTAGE(1, 1); GSTAGE(2, 2);   // depth-3 prologue

  for (int g = 0; g < 9; ++g) {
    const int kk = g * 5;
    STEP(kk + 0, 0, 3);
    STEP(kk + 1, 1, 4);
    STEP(kk + 2, 2, 0);
    STEP(kk + 3, 3, 1);
    STEP(kk + 4, 4, 2);
  }
  // tail: kk = 45,46,47 (bufs 0,1,2) — drain 8 -> 4 -> 0
  WAITVM(8); BAR(); FENCE(); COMPUTE(0); FENCE();
  WAITVM(4); BAR(); FENCE(); COMPUTE(1); FENCE();
  WAITVM(0); BAR(); FENCE(); COMPUTE(2);
#undef GSTAGE
#undef COMPUTE
#undef STEP

#pragma unroll
  for (int m = 0; m < 4; ++m) {
    const int p = p0 + wm * 64 + m * 16 + hi * 4;
#pragma unroll
    for (int n = 0; n < 4; ++n) {
      const int o = o0 + wn * 64 + n * 16 + row_in;
#pragma unroll
      for (int r = 0; r < 4; ++r)
        out[(size_t)((b * NCT) + p + r) * ND + o] = acc[m][n][r];
    }
  }
}

// ---------------------------------------------------------------------------
extern "C" void kernel_launch(void* const* d_in, const int* in_sizes, int n_in,
                              void* d_out, int out_size, void* d_ws, size_t ws_size,
                              hipStream_t stream) {
  const float* x = (const float*)d_in[0];
  const float* bank = (const float*)d_in[1];
  const float* tw = (const float*)d_in[2];
  float* out = (float*)d_out;

  char* ws = (char*)d_ws;
  __hip_bfloat16* Apad = (__hip_bfloat16*)ws;
  __hip_bfloat16* Wb = (__hip_bfloat16*)(ws + APAD_BYTES);
  __hip_bfloat16* bankB = (__hip_bfloat16*)(ws + APAD_BYTES + WB_BYTES);

  prep_kernel<<<256, 256, 0, stream>>>(bank, tw, Wb, bankB);
  cwt_kernel<<<256, 512, 0, stream>>>(x, bankB, Apad);
  gemm_kernel<<<512, 256, 0, stream>>>(Apad, Wb, out);
}